// Round 3
// baseline (912.414 us; speedup 1.0000x reference)
//
#include <hip/hip_runtime.h>
#include <stdint.h>

#define S_LEN 4096
#define NKTH  32                           // key tiles per half (64 keys each)
#define SCALE_LOG2E 0.18033688011112042f   // (1/sqrt(64)) * log2(e), folded into Q

typedef __attribute__((ext_vector_type(8))) short bf16x8;
typedef __attribute__((ext_vector_type(4))) float f32x4;

#if __has_builtin(__builtin_amdgcn_exp2f)
#define EXP2(x) __builtin_amdgcn_exp2f(x)
#else
#define EXP2(x) exp2f(x)
#endif

__device__ __forceinline__ unsigned pk2(float a, float b) {
    // round-half-up bf16 pair pack: +0x8000 then take high halves via v_perm
    unsigned ua = __builtin_bit_cast(unsigned, a) + 0x8000u;
    unsigned ub = __builtin_bit_cast(unsigned, b) + 0x8000u;
    return __builtin_amdgcn_perm(ub, ua, 0x07060302u);
}

__device__ __forceinline__ f32x4 mfma16(bf16x8 a, bf16x8 b, f32x4 c) {
    return __builtin_amdgcn_mfma_f32_16x16x32_bf16(a, b, c, 0, 0, 0);
}

// ---------------- mask packing: bool(any encoding) -> bitfield ----------------
__global__ void pack_mask_kernel(const unsigned* __restrict__ m32,
                                 unsigned long long* __restrict__ out) {
    const int lane = threadIdx.x & 63;
    const int w = threadIdx.x >> 6;
    unsigned pv = m32[lane];
    bool okw = (pv == 0u) || (pv == 1u) || (pv == 0x3F800000u);
    const bool is_word = (__ballot(okw) == ~0ull);
    const long long wbase = ((long long)blockIdx.x * 4 + w) * 4;   // u64 words
    const unsigned char* m8 = (const unsigned char*)m32;
#pragma unroll
    for (int it = 0; it < 4; ++it) {
        long long e = (wbase + it) * 64 + lane;
        bool bit = is_word ? (m32[e] != 0u) : (m8[e] != 0);
        unsigned long long bal = __ballot(bit);
        if (lane == 0) out[wbase + it] = bal;
    }
}

// ---------------- staging: global fp32 -> regs (packed bf16), 256 threads ----
// K: thread t -> row r = t>>2 (64 rows), quarter h = t&3 (cols h*16..h*16+15)
// V^T: thread t -> d = t&63, key group g = t>>6 (keys g*16..g*16+15)
__device__ __forceinline__ void pf_load(const float* __restrict__ K,
                                        const float* __restrict__ V,
                                        int bh, int k0, int t,
                                        unsigned* kb, unsigned* vb) {
    const int r = t >> 2, h = t & 3;
    const float* kp = K + (((size_t)(bh * S_LEN + k0 + r)) << 6) + h * 16;
#pragma unroll
    for (int cc = 0; cc < 2; ++cc) {
        float4 f0 = ((const float4*)kp)[cc * 2];
        float4 f1 = ((const float4*)kp)[cc * 2 + 1];
        kb[cc * 4 + 0] = pk2(f0.x, f0.y);
        kb[cc * 4 + 1] = pk2(f0.z, f0.w);
        kb[cc * 4 + 2] = pk2(f1.x, f1.y);
        kb[cc * 4 + 3] = pk2(f1.z, f1.w);
    }
    const int d = t & 63, g = t >> 6;
    const float* vp = V + (((size_t)(bh * S_LEN + k0 + g * 16)) << 6) + d;
#pragma unroll
    for (int c8 = 0; c8 < 2; ++c8) {
        float f[8];
#pragma unroll
        for (int i = 0; i < 8; ++i) f[i] = vp[(c8 * 8 + i) * 64];
        vb[c8 * 4 + 0] = pk2(f[0], f[1]);
        vb[c8 * 4 + 1] = pk2(f[2], f[3]);
        vb[c8 * 4 + 2] = pk2(f[4], f[5]);
        vb[c8 * 4 + 3] = pk2(f[6], f[7]);
    }
}

__device__ __forceinline__ void pf_store(int t, const unsigned* kb, const unsigned* vb,
                                         unsigned short* lk, unsigned short* lv) {
    const int r = t >> 2, h = t & 3;
#pragma unroll
    for (int cc = 0; cc < 2; ++cc) {
        int c = h * 2 + cc;
        uint4 st = {kb[cc * 4 + 0], kb[cc * 4 + 1], kb[cc * 4 + 2], kb[cc * 4 + 3]};
        *(uint4*)&lk[r * 64 + ((c ^ (r & 7)) << 3)] = st;
    }
    const int d = t & 63, g = t >> 6;
#pragma unroll
    for (int c8 = 0; c8 < 2; ++c8) {
        int c = g * 2 + c8;
        uint4 st = {vb[c8 * 4 + 0], vb[c8 * 4 + 1], vb[c8 * 4 + 2], vb[c8 * 4 + 3]};
        *(uint4*)&lv[d * 64 + ((c ^ (d & 7)) << 3)] = st;
    }
}

// ---------------- one 64-key tile: S^T = K·Q^T, softmax, O^T += V^T·P^T ------
// wave q-tile = 32 rows (nt in {0,1}); Q pre-scaled by scale*log2e
__device__ __forceinline__ void compute_tile(
    int kt, int q0w, int n16, int quad,
    const unsigned long long (&mrow)[2],
    const unsigned* __restrict__ rawmask,
    int use_packed, int mask_is_word,
    const unsigned short* lk, const unsigned short* lv,
    const bf16x8 (&aq)[2][2], f32x4 (&oacc)[4][2], float (&lsum)[2]) {
    const int k0 = kt * 64;
    // S^T[k'][q] : A = K rows (m = k'), B = Q rows (n = q)
    f32x4 sac[4][2];
    const f32x4 z = {0.f, 0.f, 0.f, 0.f};
#pragma unroll
    for (int mt = 0; mt < 4; ++mt)
#pragma unroll
        for (int nt = 0; nt < 2; ++nt) sac[mt][nt] = z;
#pragma unroll
    for (int kd = 0; kd < 2; ++kd) {
#pragma unroll
        for (int mt = 0; mt < 4; ++mt) {
            int row = mt * 16 + n16;
            bf16x8 ak = *(const bf16x8*)&lk[row * 64 + (((kd * 4 + quad) ^ (row & 7)) << 3)];
#pragma unroll
            for (int nt = 0; nt < 2; ++nt)
                sac[mt][nt] = mfma16(ak, aq[nt][kd], sac[mt][nt]);
        }
    }
    // softmax numerators (no running max: |logit*log2e| bounded ~12)
    unsigned pkk[4][2][2];
#pragma unroll
    for (int mt = 0; mt < 4; ++mt) {
#pragma unroll
        for (int nt = 0; nt < 2; ++nt) {
            float p[4];
#pragma unroll
            for (int reg = 0; reg < 4; ++reg) {
                float e = EXP2(sac[mt][nt][reg]);
                int pos = mt * 16 + quad * 4 + reg;
                bool bit;
                if (use_packed) {
                    bit = (mrow[nt] >> pos) & 1ull;
                } else {
                    size_t mi = (size_t)(q0w + nt * 16 + n16) * S_LEN + k0 + pos;
                    bit = mask_is_word ? (rawmask[mi] != 0u)
                                       : (((const unsigned char*)rawmask)[mi] != 0);
                }
                p[reg] = bit ? e : 0.0f;
            }
            lsum[nt] += (p[0] + p[1]) + (p[2] + p[3]);
            pkk[mt][nt][0] = pk2(p[0], p[1]);
            pkk[mt][nt][1] = pk2(p[2], p[3]);
        }
    }
    // O^T[d][q] += V^T · P^T ; P^T B-fragments built by cross-quad shuffles
    const int sl = ((quad & 1) << 5) | n16;
    const bool hi = (quad & 2) != 0;
#pragma unroll
    for (int kk = 0; kk < 2; ++kk) {
        bf16x8 av[4];
#pragma unroll
        for (int md = 0; md < 4; ++md) {
            int dr = md * 16 + n16;
            av[md] = *(const bf16x8*)&lv[dr * 64 + (((kk * 4 + quad) ^ (dr & 7)) << 3)];
        }
#pragma unroll
        for (int nt = 0; nt < 2; ++nt) {
            unsigned t0r0 = (unsigned)__shfl((int)pkk[2 * kk + 0][nt][0], sl);
            unsigned t1r0 = (unsigned)__shfl((int)pkk[2 * kk + 1][nt][0], sl);
            unsigned t0r1 = (unsigned)__shfl((int)pkk[2 * kk + 0][nt][1], sl);
            unsigned t1r1 = (unsigned)__shfl((int)pkk[2 * kk + 1][nt][1], sl);
            unsigned t0r0h = (unsigned)__shfl((int)pkk[2 * kk + 0][nt][0], sl | 16);
            unsigned t1r0h = (unsigned)__shfl((int)pkk[2 * kk + 1][nt][0], sl | 16);
            unsigned t0r1h = (unsigned)__shfl((int)pkk[2 * kk + 0][nt][1], sl | 16);
            unsigned t1r1h = (unsigned)__shfl((int)pkk[2 * kk + 1][nt][1], sl | 16);
            uint4 bb;
            bb.x = hi ? t1r0 : t0r0;
            bb.y = hi ? t1r1 : t0r1;
            bb.z = hi ? t1r0h : t0r0h;
            bb.w = hi ? t1r1h : t0r1h;
            bf16x8 pb = __builtin_bit_cast(bf16x8, bb);
#pragma unroll
            for (int md = 0; md < 4; ++md)
                oacc[md][nt] = mfma16(av[md], pb, oacc[md][nt]);
        }
    }
}

// 512 threads = 8 waves: waves 0-3 keys [0,2048), waves 4-7 keys [2048,4096),
// same 128 q rows; LDS combine at the end.
__global__ __launch_bounds__(512, 4) void attn_kernel(
    const float* __restrict__ Q, const float* __restrict__ K, const float* __restrict__ V,
    const unsigned long long* __restrict__ pm, const unsigned* __restrict__ rawmask,
    int use_packed, float* __restrict__ O) {
    __shared__ __align__(16) unsigned short smem[32768];   // 64 KB
    const int tid = threadIdx.x;
    const int lane = tid & 63;
    const int w = tid >> 6;
    const int n16 = lane & 15;
    const int quad = lane >> 4;
    const int half = w >> 2;     // key half
    const int wq = w & 3;        // q-tile within block
    const int bh = blockIdx.y;
    const int q0w = blockIdx.x * 128 + wq * 32;
    const int kbase = half * 2048;
    const int t = tid & 255;     // staging thread id within half-group

    // LDS carve: lk[half][buf], lv[half][buf] — 8 KB tiles
    unsigned short* lkp0 = smem + (half * 2 + 0) * 4096;
    unsigned short* lkp1 = smem + (half * 2 + 1) * 4096;
    unsigned short* lvp0 = smem + 16384 + (half * 2 + 0) * 4096;
    unsigned short* lvp1 = smem + 16384 + (half * 2 + 1) * 4096;

    int mask_is_word = 1;
    if (!use_packed) {
        unsigned v = rawmask[lane];
        bool okw = (v == 0u) || (v == 1u) || (v == 0x3F800000u);
        mask_is_word = (__ballot(okw) == ~0ull) ? 1 : 0;
    }

    // persistent Q fragments (B-operand), pre-scaled by scale*log2e
    bf16x8 aq[2][2];
#pragma unroll
    for (int nt = 0; nt < 2; ++nt) {
        const float* qp = Q + ((size_t)(bh * S_LEN + q0w + nt * 16 + n16) << 6);
#pragma unroll
        for (int kd = 0; kd < 2; ++kd) {
            float4 f0 = *(const float4*)(qp + kd * 32 + quad * 8);
            float4 f1 = *(const float4*)(qp + kd * 32 + quad * 8 + 4);
            uint4 u = {pk2(f0.x * SCALE_LOG2E, f0.y * SCALE_LOG2E),
                       pk2(f0.z * SCALE_LOG2E, f0.w * SCALE_LOG2E),
                       pk2(f1.x * SCALE_LOG2E, f1.y * SCALE_LOG2E),
                       pk2(f1.z * SCALE_LOG2E, f1.w * SCALE_LOG2E)};
            aq[nt][kd] = __builtin_bit_cast(bf16x8, u);
        }
    }

    f32x4 oacc[4][2];
    const f32x4 z = {0.f, 0.f, 0.f, 0.f};
#pragma unroll
    for (int md = 0; md < 4; ++md)
#pragma unroll
        for (int nt = 0; nt < 2; ++nt) oacc[md][nt] = z;
    float lsum[2] = {0.f, 0.f};

    // prime buffer 0 of this half
    unsigned kb[8], vb[8];
    pf_load(K, V, bh, kbase, t, kb, vb);
    pf_store(t, kb, vb, lkp0, lvp0);
    unsigned long long mrow_cur[2] = {0, 0}, mrow_nxt[2] = {0, 0};
    if (use_packed) {
#pragma unroll
        for (int nt = 0; nt < 2; ++nt)
            mrow_cur[nt] = pm[(size_t)(q0w + nt * 16 + n16) * 64 + half * NKTH];
    }

    for (int ktl = 0; ktl < NKTH; ++ktl) {
        const int cur = ktl & 1;
        const int ktn = (ktl + 1) & (NKTH - 1);
        const int ktg = half * NKTH + ktl;
        __syncthreads();
        pf_load(K, V, bh, kbase + ktn * 64, t, kb, vb);
        if (use_packed) {
#pragma unroll
            for (int nt = 0; nt < 2; ++nt)
                mrow_nxt[nt] = pm[(size_t)(q0w + nt * 16 + n16) * 64 + half * NKTH + ktn];
        }
        compute_tile(ktg, q0w, n16, quad, mrow_cur, rawmask, use_packed, mask_is_word,
                     cur ? lkp1 : lkp0, cur ? lvp1 : lvp0, aq, oacc, lsum);
        pf_store(t, kb, vb, cur ? lkp0 : lkp1, cur ? lvp0 : lvp1);
        mrow_cur[0] = mrow_nxt[0];
        mrow_cur[1] = mrow_nxt[1];
    }

    // ---- combine halves through LDS (stride 36 floats: 16B aligned) ----
    __syncthreads();
    float* cb = (float*)smem;
    if (half == 1) {
        float* c = cb + ((size_t)(wq * 64 + lane)) * 36;
#pragma unroll
        for (int md = 0; md < 4; ++md)
#pragma unroll
            for (int nt = 0; nt < 2; ++nt)
                *(f32x4*)(c + (md * 2 + nt) * 4) = oacc[md][nt];
        c[32] = lsum[0];
        c[33] = lsum[1];
    }
    __syncthreads();
    if (half == 0) {
        const float* c = cb + ((size_t)(wq * 64 + lane)) * 36;
#pragma unroll
        for (int md = 0; md < 4; ++md)
#pragma unroll
            for (int nt = 0; nt < 2; ++nt)
                oacc[md][nt] += *(const f32x4*)(c + (md * 2 + nt) * 4);
        lsum[0] += c[32];
        lsum[1] += c[33];

        float rcpl[2];
#pragma unroll
        for (int nt = 0; nt < 2; ++nt) {
            float l = lsum[nt];
            l += __shfl_xor(l, 16);
            l += __shfl_xor(l, 32);
            rcpl[nt] = (l > 0.f) ? (1.0f / l) : 0.0f;
        }
#pragma unroll
        for (int md = 0; md < 4; ++md)
#pragma unroll
            for (int nt = 0; nt < 2; ++nt) {
                int q = q0w + nt * 16 + n16;
                float4 o;
                o.x = oacc[md][nt][0] * rcpl[nt];
                o.y = oacc[md][nt][1] * rcpl[nt];
                o.z = oacc[md][nt][2] * rcpl[nt];
                o.w = oacc[md][nt][3] * rcpl[nt];
                *(float4*)(O + ((size_t)(bh * S_LEN + q) << 6) + md * 16 + quad * 4) = o;
            }
    }
}

extern "C" void kernel_launch(void* const* d_in, const int* in_sizes, int n_in,
                              void* d_out, int out_size, void* d_ws, size_t ws_size,
                              hipStream_t stream) {
    (void)in_sizes; (void)n_in; (void)out_size;
    const float* Q = (const float*)d_in[0];
    const float* K = (const float*)d_in[1];
    const float* V = (const float*)d_in[2];
    const void* mask = d_in[4];
    float* O = (float*)d_out;

    const size_t need = 1024 + (size_t)S_LEN * S_LEN / 8;  // 1 KB pad + 2 MB bitfield
    const int use_packed = (d_ws != nullptr && ws_size >= need) ? 1 : 0;
    unsigned long long* pmw = (unsigned long long*)((char*)d_ws + 1024);

    if (use_packed) {
        pack_mask_kernel<<<dim3(16384), 256, 0, stream>>>((const unsigned*)mask, pmw);
    }
    attn_kernel<<<dim3(S_LEN / 128, 16), 512, 0, stream>>>(
        Q, K, V, pmw, (const unsigned*)mask, use_packed, O);
}

// Round 4
// 335.205 us; speedup vs baseline: 2.7220x; 2.7220x over previous
//
#include <hip/hip_runtime.h>
#include <stdint.h>

#define S_LEN 4096
#define SCALE_LOG2E 0.18033688011112042f   // (1/sqrt(64)) * log2(e), folded into Q

typedef __attribute__((ext_vector_type(8))) short bf16x8;
typedef __attribute__((ext_vector_type(4))) float f32x4;

#if __has_builtin(__builtin_amdgcn_exp2f)
#define EXP2(x) __builtin_amdgcn_exp2f(x)
#else
#define EXP2(x) exp2f(x)
#endif

__device__ __forceinline__ unsigned pk2(float a, float b) {
    // round-half-up bf16 pair pack: +0x8000 then take high halves via v_perm
    unsigned ua = __builtin_bit_cast(unsigned, a) + 0x8000u;
    unsigned ub = __builtin_bit_cast(unsigned, b) + 0x8000u;
    return __builtin_amdgcn_perm(ub, ua, 0x07060302u);
}

__device__ __forceinline__ f32x4 mfma16(bf16x8 a, bf16x8 b, f32x4 c) {
    return __builtin_amdgcn_mfma_f32_16x16x32_bf16(a, b, c, 0, 0, 0);
}

// ---------------- mask packing: bool(any encoding) -> bitfield ----------------
__global__ void pack_mask_kernel(const unsigned* __restrict__ m32,
                                 unsigned long long* __restrict__ out) {
    const int lane = threadIdx.x & 63;
    const int w = threadIdx.x >> 6;
    unsigned pv = m32[lane];
    bool okw = (pv == 0u) || (pv == 1u) || (pv == 0x3F800000u);
    const bool is_word = (__ballot(okw) == ~0ull);
    const long long wbase = ((long long)blockIdx.x * 4 + w) * 4;   // u64 words
    const unsigned char* m8 = (const unsigned char*)m32;
#pragma unroll
    for (int it = 0; it < 4; ++it) {
        long long e = (wbase + it) * 64 + lane;
        bool bit = is_word ? (m32[e] != 0u) : (m8[e] != 0);
        unsigned long long bal = __ballot(bit);
        if (lane == 0) out[wbase + it] = bal;
    }
}

// ---------------- staging: global fp32 -> regs (packed bf16), 256 threads ----
__device__ __forceinline__ void pf_load(const float* __restrict__ K,
                                        const float* __restrict__ V,
                                        int bh, int k0, int t,
                                        unsigned* kb, unsigned* vb) {
    const int r = t >> 2, h = t & 3;
    const float* kp = K + (((size_t)(bh * S_LEN + k0 + r)) << 6) + h * 16;
#pragma unroll
    for (int cc = 0; cc < 2; ++cc) {
        float4 f0 = ((const float4*)kp)[cc * 2];
        float4 f1 = ((const float4*)kp)[cc * 2 + 1];
        kb[cc * 4 + 0] = pk2(f0.x, f0.y);
        kb[cc * 4 + 1] = pk2(f0.z, f0.w);
        kb[cc * 4 + 2] = pk2(f1.x, f1.y);
        kb[cc * 4 + 3] = pk2(f1.z, f1.w);
    }
    const int d = t & 63, g = t >> 6;
    const float* vp = V + (((size_t)(bh * S_LEN + k0 + g * 16)) << 6) + d;
#pragma unroll
    for (int c8 = 0; c8 < 2; ++c8) {
        float f[8];
#pragma unroll
        for (int i = 0; i < 8; ++i) f[i] = vp[(c8 * 8 + i) * 64];
        vb[c8 * 4 + 0] = pk2(f[0], f[1]);
        vb[c8 * 4 + 1] = pk2(f[2], f[3]);
        vb[c8 * 4 + 2] = pk2(f[4], f[5]);
        vb[c8 * 4 + 3] = pk2(f[6], f[7]);
    }
}

__device__ __forceinline__ void pf_store(int t, const unsigned* kb, const unsigned* vb,
                                         unsigned short* lk, unsigned short* lv) {
    const int r = t >> 2, h = t & 3;
#pragma unroll
    for (int cc = 0; cc < 2; ++cc) {
        int c = h * 2 + cc;
        uint4 st = {kb[cc * 4 + 0], kb[cc * 4 + 1], kb[cc * 4 + 2], kb[cc * 4 + 3]};
        *(uint4*)&lk[r * 64 + ((c ^ (r & 7)) << 3)] = st;
    }
    const int d = t & 63, g = t >> 6;
#pragma unroll
    for (int c8 = 0; c8 < 2; ++c8) {
        int c = g * 2 + c8;
        uint4 st = {vb[c8 * 4 + 0], vb[c8 * 4 + 1], vb[c8 * 4 + 2], vb[c8 * 4 + 3]};
        *(uint4*)&lv[d * 64 + ((c ^ (d & 7)) << 3)] = st;
    }
}

// ---------------- one 64-key tile: S^T = K·Q^T, softmax, O^T += V^T·P^T ------
// wave q-tile = 32 rows (nt in {0,1}); Q pre-scaled by scale*log2e
__device__ __forceinline__ void compute_tile(
    int kt, int q0w, int n16, int quad,
    const unsigned long long (&mrow)[2],
    const unsigned* __restrict__ rawmask,
    int use_packed, int mask_is_word,
    const unsigned short* lk, const unsigned short* lv,
    const bf16x8 (&aq)[2][2], f32x4 (&oacc)[4][2], float (&lsum)[2]) {
    const int k0 = kt * 64;
    // S^T[k'][q] : A = K rows (m = k'), B = Q rows (n = q)
    f32x4 sac[4][2];
    const f32x4 z = {0.f, 0.f, 0.f, 0.f};
#pragma unroll
    for (int mt = 0; mt < 4; ++mt)
#pragma unroll
        for (int nt = 0; nt < 2; ++nt) sac[mt][nt] = z;
#pragma unroll
    for (int kd = 0; kd < 2; ++kd) {
#pragma unroll
        for (int mt = 0; mt < 4; ++mt) {
            int row = mt * 16 + n16;
            bf16x8 ak = *(const bf16x8*)&lk[row * 64 + (((kd * 4 + quad) ^ (row & 7)) << 3)];
#pragma unroll
            for (int nt = 0; nt < 2; ++nt)
                sac[mt][nt] = mfma16(ak, aq[nt][kd], sac[mt][nt]);
        }
    }
    // softmax numerators (no running max: |logit*log2e| bounded ~12)
    unsigned pkk[4][2][2];
#pragma unroll
    for (int mt = 0; mt < 4; ++mt) {
#pragma unroll
        for (int nt = 0; nt < 2; ++nt) {
            float p[4];
#pragma unroll
            for (int reg = 0; reg < 4; ++reg) {
                float e = EXP2(sac[mt][nt][reg]);
                int pos = mt * 16 + quad * 4 + reg;
                bool bit;
                if (use_packed) {
                    bit = (mrow[nt] >> pos) & 1ull;
                } else {
                    size_t mi = (size_t)(q0w + nt * 16 + n16) * S_LEN + k0 + pos;
                    bit = mask_is_word ? (rawmask[mi] != 0u)
                                       : (((const unsigned char*)rawmask)[mi] != 0);
                }
                p[reg] = bit ? e : 0.0f;
            }
            lsum[nt] += (p[0] + p[1]) + (p[2] + p[3]);
            pkk[mt][nt][0] = pk2(p[0], p[1]);
            pkk[mt][nt][1] = pk2(p[2], p[3]);
        }
    }
    // O^T[d][q] += V^T · P^T ; P^T B-fragments built by cross-quad shuffles
    const int sl = ((quad & 1) << 5) | n16;
    const bool hi = (quad & 2) != 0;
#pragma unroll
    for (int kk = 0; kk < 2; ++kk) {
        bf16x8 av[4];
#pragma unroll
        for (int md = 0; md < 4; ++md) {
            int dr = md * 16 + n16;
            av[md] = *(const bf16x8*)&lv[dr * 64 + (((kk * 4 + quad) ^ (dr & 7)) << 3)];
        }
#pragma unroll
        for (int nt = 0; nt < 2; ++nt) {
            unsigned t0r0 = (unsigned)__shfl((int)pkk[2 * kk + 0][nt][0], sl);
            unsigned t1r0 = (unsigned)__shfl((int)pkk[2 * kk + 1][nt][0], sl);
            unsigned t0r1 = (unsigned)__shfl((int)pkk[2 * kk + 0][nt][1], sl);
            unsigned t1r1 = (unsigned)__shfl((int)pkk[2 * kk + 1][nt][1], sl);
            unsigned t0r0h = (unsigned)__shfl((int)pkk[2 * kk + 0][nt][0], sl | 16);
            unsigned t1r0h = (unsigned)__shfl((int)pkk[2 * kk + 1][nt][0], sl | 16);
            unsigned t0r1h = (unsigned)__shfl((int)pkk[2 * kk + 0][nt][1], sl | 16);
            unsigned t1r1h = (unsigned)__shfl((int)pkk[2 * kk + 1][nt][1], sl | 16);
            uint4 bb;
            bb.x = hi ? t1r0 : t0r0;
            bb.y = hi ? t1r1 : t0r1;
            bb.z = hi ? t1r0h : t0r0h;
            bb.w = hi ? t1r1h : t0r1h;
            bf16x8 pb = __builtin_bit_cast(bf16x8, bb);
#pragma unroll
            for (int md = 0; md < 4; ++md)
                oacc[md][nt] = mfma16(av[md], pb, oacc[md][nt]);
        }
    }
}

__device__ __forceinline__ void load_q_frags(const float* __restrict__ Q, int bh, int q0w,
                                             int n16, int quad, bf16x8 (&aq)[2][2]) {
#pragma unroll
    for (int nt = 0; nt < 2; ++nt) {
        const float* qp = Q + ((size_t)(bh * S_LEN + q0w + nt * 16 + n16) << 6);
#pragma unroll
        for (int kd = 0; kd < 2; ++kd) {
            float4 f0 = *(const float4*)(qp + kd * 32 + quad * 8);
            float4 f1 = *(const float4*)(qp + kd * 32 + quad * 8 + 4);
            uint4 u = {pk2(f0.x * SCALE_LOG2E, f0.y * SCALE_LOG2E),
                       pk2(f0.z * SCALE_LOG2E, f0.w * SCALE_LOG2E),
                       pk2(f1.x * SCALE_LOG2E, f1.y * SCALE_LOG2E),
                       pk2(f1.z * SCALE_LOG2E, f1.w * SCALE_LOG2E)};
            aq[nt][kd] = __builtin_bit_cast(bf16x8, u);
        }
    }
}

// ============ K-split partial kernel: blockIdx.z = key half, packed mask =====
__global__ __launch_bounds__(256, 2) void attn_partial(
    const float* __restrict__ Q, const float* __restrict__ K, const float* __restrict__ V,
    const unsigned long long* __restrict__ pm,
    float* __restrict__ Opart, float* __restrict__ Lpart) {
    __shared__ __align__(16) unsigned short lk[2][64 * 64];
    __shared__ __align__(16) unsigned short lv[2][64 * 64];
    const int tid = threadIdx.x;
    const int lane = tid & 63;
    const int w = tid >> 6;
    const int n16 = lane & 15;
    const int quad = lane >> 4;
    const int bh = blockIdx.y;
    const int half = blockIdx.z;
    const int q0w = blockIdx.x * 128 + w * 32;
    const int kbase = half * 2048;

    bf16x8 aq[2][2];
    load_q_frags(Q, bh, q0w, n16, quad, aq);

    f32x4 oacc[4][2];
    const f32x4 z = {0.f, 0.f, 0.f, 0.f};
#pragma unroll
    for (int md = 0; md < 4; ++md)
#pragma unroll
        for (int nt = 0; nt < 2; ++nt) oacc[md][nt] = z;
    float lsum[2] = {0.f, 0.f};

    unsigned kb[8], vb[8];
    pf_load(K, V, bh, kbase, tid, kb, vb);
    pf_store(tid, kb, vb, lk[0], lv[0]);
    unsigned long long mrow_cur[2], mrow_nxt[2];
#pragma unroll
    for (int nt = 0; nt < 2; ++nt)
        mrow_cur[nt] = pm[(size_t)(q0w + nt * 16 + n16) * 64 + half * 32];

    for (int ktl = 0; ktl < 32; ++ktl) {
        const int cur = ktl & 1;
        const int ktn = (ktl + 1) & 31;
        __syncthreads();
        pf_load(K, V, bh, kbase + ktn * 64, tid, kb, vb);
#pragma unroll
        for (int nt = 0; nt < 2; ++nt)
            mrow_nxt[nt] = pm[(size_t)(q0w + nt * 16 + n16) * 64 + half * 32 + ktn];
        compute_tile(half * 32 + ktl, q0w, n16, quad, mrow_cur, nullptr, 1, 1,
                     lk[cur], lv[cur], aq, oacc, lsum);
        pf_store(tid, kb, vb, lk[cur ^ 1], lv[cur ^ 1]);
        mrow_cur[0] = mrow_nxt[0];
        mrow_cur[1] = mrow_nxt[1];
    }

    // store raw partial O^T (no normalization) + reduced row sums
#pragma unroll
    for (int nt = 0; nt < 2; ++nt) {
        float l = lsum[nt];
        l += __shfl_xor(l, 16);
        l += __shfl_xor(l, 32);
        int q = q0w + nt * 16 + n16;
        if (quad == 0) Lpart[((size_t)(half * 16 + bh) << 12) + q] = l;
#pragma unroll
        for (int md = 0; md < 4; ++md) {
            float4 o;
            o.x = oacc[md][nt][0];
            o.y = oacc[md][nt][1];
            o.z = oacc[md][nt][2];
            o.w = oacc[md][nt][3];
            *(float4*)(Opart + (((size_t)(half * 16 + bh) << 12) + q) * 64 +
                       md * 16 + quad * 4) = o;
        }
    }
}

// ============ combine: O = (O0 + O1) / (l0 + l1) =============================
__global__ __launch_bounds__(256) void combine_kernel(
    const float* __restrict__ Opart, const float* __restrict__ Lpart,
    float* __restrict__ O) {
    const int row = blockIdx.x * 16 + (threadIdx.x >> 4);      // bh*4096+q
    const int d4 = (threadIdx.x & 15) * 4;
    const float* p0 = Opart + (size_t)row * 64 + d4;
    const float* p1 = p0 + (size_t)16 * S_LEN * 64;
    float4 a = *(const float4*)p0;
    float4 b = *(const float4*)p1;
    float l = Lpart[row] + Lpart[16 * S_LEN + row];
    float r = (l > 0.f) ? (1.0f / l) : 0.0f;
    float4 o;
    o.x = (a.x + b.x) * r;
    o.y = (a.y + b.y) * r;
    o.z = (a.z + b.z) * r;
    o.w = (a.w + b.w) * r;
    *(float4*)(O + (size_t)row * 64 + d4) = o;
}

// ============ fallback: single kernel, full key range (R2 structure) =========
__global__ __launch_bounds__(256, 2) void attn_kernel(
    const float* __restrict__ Q, const float* __restrict__ K, const float* __restrict__ V,
    const unsigned long long* __restrict__ pm, const unsigned* __restrict__ rawmask,
    int use_packed, float* __restrict__ O) {
    __shared__ __align__(16) unsigned short lk[2][64 * 64];
    __shared__ __align__(16) unsigned short lv[2][64 * 64];
    const int tid = threadIdx.x;
    const int lane = tid & 63;
    const int w = tid >> 6;
    const int n16 = lane & 15;
    const int quad = lane >> 4;
    const int bh = blockIdx.y;
    const int q0w = blockIdx.x * 128 + w * 32;

    int mask_is_word = 1;
    if (!use_packed) {
        unsigned v = rawmask[lane];
        bool okw = (v == 0u) || (v == 1u) || (v == 0x3F800000u);
        mask_is_word = (__ballot(okw) == ~0ull) ? 1 : 0;
    }

    bf16x8 aq[2][2];
    load_q_frags(Q, bh, q0w, n16, quad, aq);

    f32x4 oacc[4][2];
    const f32x4 z = {0.f, 0.f, 0.f, 0.f};
#pragma unroll
    for (int md = 0; md < 4; ++md)
#pragma unroll
        for (int nt = 0; nt < 2; ++nt) oacc[md][nt] = z;
    float lsum[2] = {0.f, 0.f};

    unsigned kb[8], vb[8];
    pf_load(K, V, bh, 0, tid, kb, vb);
    pf_store(tid, kb, vb, lk[0], lv[0]);
    unsigned long long mrow_cur[2] = {0, 0}, mrow_nxt[2] = {0, 0};
    if (use_packed) {
#pragma unroll
        for (int nt = 0; nt < 2; ++nt)
            mrow_cur[nt] = pm[(size_t)(q0w + nt * 16 + n16) * 64];
    }

    for (int kt = 0; kt < 64; ++kt) {
        const int cur = kt & 1;
        const int ktn = (kt + 1) & 63;
        __syncthreads();
        pf_load(K, V, bh, ktn * 64, tid, kb, vb);
        if (use_packed) {
#pragma unroll
            for (int nt = 0; nt < 2; ++nt)
                mrow_nxt[nt] = pm[(size_t)(q0w + nt * 16 + n16) * 64 + ktn];
        }
        compute_tile(kt, q0w, n16, quad, mrow_cur, rawmask, use_packed, mask_is_word,
                     lk[cur], lv[cur], aq, oacc, lsum);
        pf_store(tid, kb, vb, lk[cur ^ 1], lv[cur ^ 1]);
        mrow_cur[0] = mrow_nxt[0];
        mrow_cur[1] = mrow_nxt[1];
    }

    float rcpl[2];
#pragma unroll
    for (int nt = 0; nt < 2; ++nt) {
        float l = lsum[nt];
        l += __shfl_xor(l, 16);
        l += __shfl_xor(l, 32);
        rcpl[nt] = (l > 0.f) ? (1.0f / l) : 0.0f;
    }
#pragma unroll
    for (int md = 0; md < 4; ++md)
#pragma unroll
        for (int nt = 0; nt < 2; ++nt) {
            int q = q0w + nt * 16 + n16;
            float4 o;
            o.x = oacc[md][nt][0] * rcpl[nt];
            o.y = oacc[md][nt][1] * rcpl[nt];
            o.z = oacc[md][nt][2] * rcpl[nt];
            o.w = oacc[md][nt][3] * rcpl[nt];
            *(float4*)(O + ((size_t)(bh * S_LEN + q) << 6) + md * 16 + quad * 4) = o;
        }
}

extern "C" void kernel_launch(void* const* d_in, const int* in_sizes, int n_in,
                              void* d_out, int out_size, void* d_ws, size_t ws_size,
                              hipStream_t stream) {
    (void)in_sizes; (void)n_in; (void)out_size;
    const float* Q = (const float*)d_in[0];
    const float* K = (const float*)d_in[1];
    const float* V = (const float*)d_in[2];
    const void* mask = d_in[4];
    float* O = (float*)d_out;

    const size_t bitfield_bytes = (size_t)S_LEN * S_LEN / 8;       // 2 MB
    const size_t opart_bytes = (size_t)2 * 16 * S_LEN * 64 * 4;    // 33.55 MB
    const size_t lpart_bytes = (size_t)2 * 16 * S_LEN * 4;         // 0.52 MB
    const size_t need_packed = 1024 + bitfield_bytes;
    const size_t need_split = need_packed + opart_bytes + lpart_bytes;

    unsigned long long* pmw = (unsigned long long*)((char*)d_ws + 1024);
    float* opart = (float*)((char*)d_ws + need_packed);
    float* lpart = opart + (size_t)2 * 16 * S_LEN * 64;

    if (d_ws != nullptr && ws_size >= need_split) {
        pack_mask_kernel<<<dim3(16384), 256, 0, stream>>>((const unsigned*)mask, pmw);
        attn_partial<<<dim3(S_LEN / 128, 16, 2), 256, 0, stream>>>(
            Q, K, V, pmw, opart, lpart);
        combine_kernel<<<dim3(16 * S_LEN / 16), 256, 0, stream>>>(opart, lpart, O);
    } else if (d_ws != nullptr && ws_size >= need_packed) {
        pack_mask_kernel<<<dim3(16384), 256, 0, stream>>>((const unsigned*)mask, pmw);
        attn_kernel<<<dim3(S_LEN / 128, 16), 256, 0, stream>>>(
            Q, K, V, pmw, (const unsigned*)mask, 1, O);
    } else {
        attn_kernel<<<dim3(S_LEN / 128, 16), 256, 0, stream>>>(
            Q, K, V, nullptr, (const unsigned*)mask, 0, O);
    }
}

// Round 5
// 304.267 us; speedup vs baseline: 2.9987x; 1.1017x over previous
//
#include <hip/hip_runtime.h>
#include <stdint.h>

#define S_LEN 4096
#define SCALE_LOG2E 0.18033688011112042f   // (1/sqrt(64)) * log2(e), folded into Q

typedef __attribute__((ext_vector_type(8))) short bf16x8;
typedef __attribute__((ext_vector_type(4))) float f32x4;

#if __has_builtin(__builtin_amdgcn_exp2f)
#define EXP2(x) __builtin_amdgcn_exp2f(x)
#else
#define EXP2(x) exp2f(x)
#endif

__device__ __forceinline__ unsigned pk2(float a, float b) {
    // round-half-up bf16 pair pack: +0x8000 then take high halves via v_perm
    unsigned ua = __builtin_bit_cast(unsigned, a) + 0x8000u;
    unsigned ub = __builtin_bit_cast(unsigned, b) + 0x8000u;
    return __builtin_amdgcn_perm(ub, ua, 0x07060302u);
}

__device__ __forceinline__ f32x4 mfma16(bf16x8 a, bf16x8 b, f32x4 c) {
    return __builtin_amdgcn_mfma_f32_16x16x32_bf16(a, b, c, 0, 0, 0);
}

// ------------- mask packing: bool(any encoding) -> bitfield, [kt][q] layout --
__global__ void pack_mask_kernel(const unsigned* __restrict__ m32,
                                 unsigned long long* __restrict__ out) {
    const int lane = threadIdx.x & 63;
    const int w = threadIdx.x >> 6;
    unsigned pv = m32[lane];
    bool okw = (pv == 0u) || (pv == 1u) || (pv == 0x3F800000u);
    const bool is_word = (__ballot(okw) == ~0ull);
    const long long wbase = ((long long)blockIdx.x * 4 + w) * 4;   // u64 words (q*64+kt)
    const unsigned char* m8 = (const unsigned char*)m32;
#pragma unroll
    for (int it = 0; it < 4; ++it) {
        const long long word = wbase + it;
        long long e = word * 64 + lane;
        bool bit = is_word ? (m32[e] != 0u) : (m8[e] != 0);
        unsigned long long bal = __ballot(bit);
        if (lane == 0) {
            long long q = word >> 6, kt = word & 63;
            out[kt * S_LEN + q] = bal;   // transposed: coalesced reads in attn
        }
    }
}

// ---------------- staging: global fp32 -> regs (packed bf16), 256 threads ----
__device__ __forceinline__ void pf_load(const float* __restrict__ K,
                                        const float* __restrict__ V,
                                        int bh, int k0, int t,
                                        unsigned* kb, unsigned* vb) {
    const int r = t >> 2, h = t & 3;
    const float* kp = K + (((size_t)(bh * S_LEN + k0 + r)) << 6) + h * 16;
#pragma unroll
    for (int cc = 0; cc < 2; ++cc) {
        float4 f0 = ((const float4*)kp)[cc * 2];
        float4 f1 = ((const float4*)kp)[cc * 2 + 1];
        kb[cc * 4 + 0] = pk2(f0.x, f0.y);
        kb[cc * 4 + 1] = pk2(f0.z, f0.w);
        kb[cc * 4 + 2] = pk2(f1.x, f1.y);
        kb[cc * 4 + 3] = pk2(f1.z, f1.w);
    }
    const int d = t & 63, g = t >> 6;
    const float* vp = V + (((size_t)(bh * S_LEN + k0 + g * 16)) << 6) + d;
#pragma unroll
    for (int c8 = 0; c8 < 2; ++c8) {
        float f[8];
#pragma unroll
        for (int i = 0; i < 8; ++i) f[i] = vp[(c8 * 8 + i) * 64];
        vb[c8 * 4 + 0] = pk2(f[0], f[1]);
        vb[c8 * 4 + 1] = pk2(f[2], f[3]);
        vb[c8 * 4 + 2] = pk2(f[4], f[5]);
        vb[c8 * 4 + 3] = pk2(f[6], f[7]);
    }
}

__device__ __forceinline__ void pf_store(int t, const unsigned* kb, const unsigned* vb,
                                         unsigned short* lk, unsigned short* lv) {
    const int r = t >> 2, h = t & 3;
#pragma unroll
    for (int cc = 0; cc < 2; ++cc) {
        int c = h * 2 + cc;
        uint4 st = {kb[cc * 4 + 0], kb[cc * 4 + 1], kb[cc * 4 + 2], kb[cc * 4 + 3]};
        *(uint4*)&lk[r * 64 + ((c ^ (r & 7)) << 3)] = st;
    }
    const int d = t & 63, g = t >> 6;
#pragma unroll
    for (int c8 = 0; c8 < 2; ++c8) {
        int c = g * 2 + c8;
        uint4 st = {vb[c8 * 4 + 0], vb[c8 * 4 + 1], vb[c8 * 4 + 2], vb[c8 * 4 + 3]};
        *(uint4*)&lv[d * 64 + ((c ^ (d & 7)) << 3)] = st;
    }
}

// ---------------- one 64-key tile: S^T = K·Q^T, softmax, O^T += V^T·P^T ------
// wave q-tile = 32 rows (nt in {0,1}); Q pre-scaled by scale*log2e.
// P transposed C-layout -> B-operand layout via per-wave private LDS (lp),
// no barrier needed (same-wave lgkm ordering).
__device__ __forceinline__ void compute_tile(
    int kt, int q0w, int n16, int quad,
    const unsigned long long (&mrow)[2],
    const unsigned* __restrict__ rawmask,
    int use_packed, int mask_is_word,
    const unsigned short* lk, const unsigned short* lv, unsigned short* lp,
    const bf16x8 (&aq)[2][2], f32x4 (&oacc)[4][2], float (&lsum)[2]) {
    const int k0 = kt * 64;
    // S^T[k'][q] : A = K rows (m = k'), B = Q rows (n = q)
    f32x4 sac[4][2];
    const f32x4 z = {0.f, 0.f, 0.f, 0.f};
#pragma unroll
    for (int mt = 0; mt < 4; ++mt)
#pragma unroll
        for (int nt = 0; nt < 2; ++nt) sac[mt][nt] = z;
#pragma unroll
    for (int kd = 0; kd < 2; ++kd) {
#pragma unroll
        for (int mt = 0; mt < 4; ++mt) {
            int row = mt * 16 + n16;
            bf16x8 ak = *(const bf16x8*)&lk[row * 64 + (((kd * 4 + quad) ^ (row & 7)) << 3)];
#pragma unroll
            for (int nt = 0; nt < 2; ++nt)
                sac[mt][nt] = mfma16(ak, aq[nt][kd], sac[mt][nt]);
        }
    }
    // softmax numerators (no running max: |logit*log2e| bounded ~12);
    // write P pairs straight to lp in [q:32][k':64] rows (128B), 16B-chunk XOR swizzle
#pragma unroll
    for (int mt = 0; mt < 4; ++mt) {
#pragma unroll
        for (int nt = 0; nt < 2; ++nt) {
            float p[4];
#pragma unroll
            for (int reg = 0; reg < 4; ++reg) {
                float e = EXP2(sac[mt][nt][reg]);
                int pos = mt * 16 + quad * 4 + reg;
                bool bit;
                if (use_packed) {
                    bit = (mrow[nt] >> pos) & 1ull;
                } else {
                    size_t mi = (size_t)(q0w + nt * 16 + n16) * S_LEN + k0 + pos;
                    bit = mask_is_word ? (rawmask[mi] != 0u)
                                       : (((const unsigned char*)rawmask)[mi] != 0);
                }
                p[reg] = bit ? e : 0.0f;
            }
            lsum[nt] += (p[0] + p[1]) + (p[2] + p[3]);
            uint2 pr = {pk2(p[0], p[1]), pk2(p[2], p[3])};
            const int r = nt * 16 + n16;
            const int chunk = (mt * 2 + (quad >> 1)) ^ (n16 & 7);
            *(uint2*)((char*)lp + r * 128 + chunk * 16 + (quad & 1) * 8) = pr;
        }
    }
    // O^T[d][q] += V^T · P^T ; P^T B-fragments read back from lp
#pragma unroll
    for (int kk = 0; kk < 2; ++kk) {
        bf16x8 av[4];
#pragma unroll
        for (int md = 0; md < 4; ++md) {
            int dr = md * 16 + n16;
            av[md] = *(const bf16x8*)&lv[dr * 64 + (((kk * 4 + quad) ^ (dr & 7)) << 3)];
        }
#pragma unroll
        for (int nt = 0; nt < 2; ++nt) {
            const int r = nt * 16 + n16;
            const int chunk = (kk * 4 + quad) ^ (n16 & 7);
            bf16x8 pb = *(const bf16x8*)((const char*)lp + r * 128 + chunk * 16);
#pragma unroll
            for (int md = 0; md < 4; ++md)
                oacc[md][nt] = mfma16(av[md], pb, oacc[md][nt]);
        }
    }
}

__device__ __forceinline__ void load_q_frags(const float* __restrict__ Q, int bh, int q0w,
                                             int n16, int quad, bf16x8 (&aq)[2][2]) {
#pragma unroll
    for (int nt = 0; nt < 2; ++nt) {
        const float* qp = Q + ((size_t)(bh * S_LEN + q0w + nt * 16 + n16) << 6);
#pragma unroll
        for (int kd = 0; kd < 2; ++kd) {
            float4 f0 = *(const float4*)(qp + kd * 32 + quad * 8);
            float4 f1 = *(const float4*)(qp + kd * 32 + quad * 8 + 4);
            uint4 u = {pk2(f0.x * SCALE_LOG2E, f0.y * SCALE_LOG2E),
                       pk2(f0.z * SCALE_LOG2E, f0.w * SCALE_LOG2E),
                       pk2(f1.x * SCALE_LOG2E, f1.y * SCALE_LOG2E),
                       pk2(f1.z * SCALE_LOG2E, f1.w * SCALE_LOG2E)};
            aq[nt][kd] = __builtin_bit_cast(bf16x8, u);
        }
    }
}

// ============ K-split partial kernel: blockIdx.z = key half, packed mask =====
__global__ __launch_bounds__(256, 3) void attn_partial(
    const float* __restrict__ Q, const float* __restrict__ K, const float* __restrict__ V,
    const unsigned long long* __restrict__ pm,
    float* __restrict__ Opart, float* __restrict__ Lpart) {
    __shared__ __align__(16) unsigned short lk[2][64 * 64];
    __shared__ __align__(16) unsigned short lv[2][64 * 64];
    __shared__ __align__(16) unsigned short lpbuf[4][32 * 64];
    const int tid = threadIdx.x;
    const int lane = tid & 63;
    const int w = tid >> 6;
    const int n16 = lane & 15;
    const int quad = lane >> 4;
    const int bh = blockIdx.y;
    const int half = blockIdx.z;
    const int q0w = blockIdx.x * 128 + w * 32;
    const int kbase = half * 2048;
    unsigned short* lp = lpbuf[w];

    bf16x8 aq[2][2];
    load_q_frags(Q, bh, q0w, n16, quad, aq);

    f32x4 oacc[4][2];
    const f32x4 z = {0.f, 0.f, 0.f, 0.f};
#pragma unroll
    for (int md = 0; md < 4; ++md)
#pragma unroll
        for (int nt = 0; nt < 2; ++nt) oacc[md][nt] = z;
    float lsum[2] = {0.f, 0.f};

    unsigned kb[8], vb[8];
    pf_load(K, V, bh, kbase, tid, kb, vb);
    pf_store(tid, kb, vb, lk[0], lv[0]);
    unsigned long long mrow_cur[2], mrow_nxt[2];
#pragma unroll
    for (int nt = 0; nt < 2; ++nt)
        mrow_cur[nt] = pm[(size_t)(half * 32) * S_LEN + q0w + nt * 16 + n16];

    for (int ktl = 0; ktl < 32; ++ktl) {
        const int cur = ktl & 1;
        const int ktn = (ktl + 1) & 31;
        __syncthreads();
        pf_load(K, V, bh, kbase + ktn * 64, tid, kb, vb);
#pragma unroll
        for (int nt = 0; nt < 2; ++nt)
            mrow_nxt[nt] = pm[(size_t)(half * 32 + ktn) * S_LEN + q0w + nt * 16 + n16];
        compute_tile(half * 32 + ktl, q0w, n16, quad, mrow_cur, nullptr, 1, 1,
                     lk[cur], lv[cur], lp, aq, oacc, lsum);
        pf_store(tid, kb, vb, lk[cur ^ 1], lv[cur ^ 1]);
        mrow_cur[0] = mrow_nxt[0];
        mrow_cur[1] = mrow_nxt[1];
    }

    // store raw partial O^T (no normalization) + reduced row sums
#pragma unroll
    for (int nt = 0; nt < 2; ++nt) {
        float l = lsum[nt];
        l += __shfl_xor(l, 16);
        l += __shfl_xor(l, 32);
        int q = q0w + nt * 16 + n16;
        if (quad == 0) Lpart[((size_t)(half * 16 + bh) << 12) + q] = l;
#pragma unroll
        for (int md = 0; md < 4; ++md) {
            float4 o;
            o.x = oacc[md][nt][0];
            o.y = oacc[md][nt][1];
            o.z = oacc[md][nt][2];
            o.w = oacc[md][nt][3];
            *(float4*)(Opart + (((size_t)(half * 16 + bh) << 12) + q) * 64 +
                       md * 16 + quad * 4) = o;
        }
    }
}

// ============ combine: O = (O0 + O1) / (l0 + l1) =============================
__global__ __launch_bounds__(256) void combine_kernel(
    const float* __restrict__ Opart, const float* __restrict__ Lpart,
    float* __restrict__ O) {
    const int row = blockIdx.x * 16 + (threadIdx.x >> 4);      // bh*4096+q
    const int d4 = (threadIdx.x & 15) * 4;
    const float* p0 = Opart + (size_t)row * 64 + d4;
    const float* p1 = p0 + (size_t)16 * S_LEN * 64;
    float4 a = *(const float4*)p0;
    float4 b = *(const float4*)p1;
    float l = Lpart[row] + Lpart[16 * S_LEN + row];
    float r = (l > 0.f) ? (1.0f / l) : 0.0f;
    float4 o;
    o.x = (a.x + b.x) * r;
    o.y = (a.y + b.y) * r;
    o.z = (a.z + b.z) * r;
    o.w = (a.w + b.w) * r;
    *(float4*)(O + (size_t)row * 64 + d4) = o;
}

// ============ fallback: single kernel, full key range ========================
__global__ __launch_bounds__(256, 3) void attn_kernel(
    const float* __restrict__ Q, const float* __restrict__ K, const float* __restrict__ V,
    const unsigned long long* __restrict__ pm, const unsigned* __restrict__ rawmask,
    int use_packed, float* __restrict__ O) {
    __shared__ __align__(16) unsigned short lk[2][64 * 64];
    __shared__ __align__(16) unsigned short lv[2][64 * 64];
    __shared__ __align__(16) unsigned short lpbuf[4][32 * 64];
    const int tid = threadIdx.x;
    const int lane = tid & 63;
    const int w = tid >> 6;
    const int n16 = lane & 15;
    const int quad = lane >> 4;
    const int bh = blockIdx.y;
    const int q0w = blockIdx.x * 128 + w * 32;
    unsigned short* lp = lpbuf[w];

    int mask_is_word = 1;
    if (!use_packed) {
        unsigned v = rawmask[lane];
        bool okw = (v == 0u) || (v == 1u) || (v == 0x3F800000u);
        mask_is_word = (__ballot(okw) == ~0ull) ? 1 : 0;
    }

    bf16x8 aq[2][2];
    load_q_frags(Q, bh, q0w, n16, quad, aq);

    f32x4 oacc[4][2];
    const f32x4 z = {0.f, 0.f, 0.f, 0.f};
#pragma unroll
    for (int md = 0; md < 4; ++md)
#pragma unroll
        for (int nt = 0; nt < 2; ++nt) oacc[md][nt] = z;
    float lsum[2] = {0.f, 0.f};

    unsigned kb[8], vb[8];
    pf_load(K, V, bh, 0, tid, kb, vb);
    pf_store(tid, kb, vb, lk[0], lv[0]);
    unsigned long long mrow_cur[2] = {0, 0}, mrow_nxt[2] = {0, 0};
    if (use_packed) {
#pragma unroll
        for (int nt = 0; nt < 2; ++nt)
            mrow_cur[nt] = pm[(size_t)0 * S_LEN + q0w + nt * 16 + n16];
    }

    for (int kt = 0; kt < 64; ++kt) {
        const int cur = kt & 1;
        const int ktn = (kt + 1) & 63;
        __syncthreads();
        pf_load(K, V, bh, ktn * 64, tid, kb, vb);
        if (use_packed) {
#pragma unroll
            for (int nt = 0; nt < 2; ++nt)
                mrow_nxt[nt] = pm[(size_t)ktn * S_LEN + q0w + nt * 16 + n16];
        }
        compute_tile(kt, q0w, n16, quad, mrow_cur, rawmask, use_packed, mask_is_word,
                     lk[cur], lv[cur], lp, aq, oacc, lsum);
        pf_store(tid, kb, vb, lk[cur ^ 1], lv[cur ^ 1]);
        mrow_cur[0] = mrow_nxt[0];
        mrow_cur[1] = mrow_nxt[1];
    }

    float rcpl[2];
#pragma unroll
    for (int nt = 0; nt < 2; ++nt) {
        float l = lsum[nt];
        l += __shfl_xor(l, 16);
        l += __shfl_xor(l, 32);
        rcpl[nt] = (l > 0.f) ? (1.0f / l) : 0.0f;
    }
#pragma unroll
    for (int md = 0; md < 4; ++md)
#pragma unroll
        for (int nt = 0; nt < 2; ++nt) {
            int q = q0w + nt * 16 + n16;
            float4 o;
            o.x = oacc[md][nt][0] * rcpl[nt];
            o.y = oacc[md][nt][1] * rcpl[nt];
            o.z = oacc[md][nt][2] * rcpl[nt];
            o.w = oacc[md][nt][3] * rcpl[nt];
            *(float4*)(O + ((size_t)(bh * S_LEN + q) << 6) + md * 16 + quad * 4) = o;
        }
}

extern "C" void kernel_launch(void* const* d_in, const int* in_sizes, int n_in,
                              void* d_out, int out_size, void* d_ws, size_t ws_size,
                              hipStream_t stream) {
    (void)in_sizes; (void)n_in; (void)out_size;
    const float* Q = (const float*)d_in[0];
    const float* K = (const float*)d_in[1];
    const float* V = (const float*)d_in[2];
    const void* mask = d_in[4];
    float* O = (float*)d_out;

    const size_t bitfield_bytes = (size_t)S_LEN * S_LEN / 8;       // 2 MB
    const size_t opart_bytes = (size_t)2 * 16 * S_LEN * 64 * 4;    // 33.55 MB
    const size_t lpart_bytes = (size_t)2 * 16 * S_LEN * 4;         // 0.52 MB
    const size_t need_packed = 1024 + bitfield_bytes;
    const size_t need_split = need_packed + opart_bytes + lpart_bytes;

    unsigned long long* pmw = (unsigned long long*)((char*)d_ws + 1024);
    float* opart = (float*)((char*)d_ws + need_packed);
    float* lpart = opart + (size_t)2 * 16 * S_LEN * 64;

    if (d_ws != nullptr && ws_size >= need_split) {
        pack_mask_kernel<<<dim3(16384), 256, 0, stream>>>((const unsigned*)mask, pmw);
        attn_partial<<<dim3(S_LEN / 128, 16, 2), 256, 0, stream>>>(
            Q, K, V, pmw, opart, lpart);
        combine_kernel<<<dim3(16 * S_LEN / 16), 256, 0, stream>>>(opart, lpart, O);
    } else if (d_ws != nullptr && ws_size >= need_packed) {
        pack_mask_kernel<<<dim3(16384), 256, 0, stream>>>((const unsigned*)mask, pmw);
        attn_kernel<<<dim3(S_LEN / 128, 16), 256, 0, stream>>>(
            Q, K, V, pmw, (const unsigned*)mask, 1, O);
    } else {
        attn_kernel<<<dim3(S_LEN / 128, 16), 256, 0, stream>>>(
            Q, K, V, nullptr, (const unsigned*)mask, 0, O);
    }
}